// Round 12
// baseline (181.383 us; speedup 1.0000x reference)
//
#include <hip/hip_runtime.h>

// Problem constants (B=4, C=256, H=W=64 -> T=4096)
constexpr int kB  = 4;
constexpr int kC  = 256;
constexpr int kT  = 4096;
constexpr int kG  = 16;
constexpr int kCg = kC / kG;   // 16 channels per group
constexpr int kH  = 4;         // heads
constexpr int kCh = kC / kH;   // 64 channels per head
constexpr float kEps = 1e-5f;
// q scale: 1/8 (=scale^2) folded with log2(e) for exp2-domain softmax
constexpr float kQScale = 0.125f * 1.4426950408889634f;

typedef short bf16x8 __attribute__((ext_vector_type(8)));
typedef float f32x4  __attribute__((ext_vector_type(4)));
typedef float f32x16 __attribute__((ext_vector_type(16)));

union PunP { uint4 u; bf16x8 f; };

__device__ inline unsigned short f2bf(float f) {
    union { float f; unsigned u; } v; v.f = f;
    unsigned r = v.u + 0x7fffu + ((v.u >> 16) & 1u);   // RNE
    return (unsigned short)(r >> 16);
}
__device__ inline unsigned pk2bf(float a, float b) {
    return (unsigned)f2bf(a) | ((unsigned)f2bf(b) << 16);
}
// truncating pack of two fp32 -> bf16x2 in ONE v_perm_b32 (high halves)
__device__ inline unsigned pk2bf_trunc(float a, float b) {
    return __builtin_amdgcn_perm(__float_as_uint(b), __float_as_uint(a), 0x07060302u);
}
// v_permlane32_swap_b32: a[32:63] <-> b[0:31].
__device__ inline void pls32(unsigned& a, unsigned& b) {
    __asm__("v_permlane32_swap_b32 %0, %1" : "+v"(a), "+v"(b));
}
// async global->LDS DMA, 16B per lane: LDS dest = uniform base + lane*16.
__device__ inline void llds16(const unsigned short* g, unsigned short* l) {
    __builtin_amdgcn_global_load_lds(
        (const __attribute__((address_space(1))) unsigned int*)(g),
        (__attribute__((address_space(3))) unsigned int*)(l), 16, 0, 0);
}

// ---------------------------------------------------------------------------
// Kernel 1 (R21): GroupNorm statistics + weight fp32->bf16 convert.
// Partial sums to DISJOINT slots stats[(bg*4+part)*2] (no atomics, no
// memset). 256 stat blocks + 128 convert blocks.
// ---------------------------------------------------------------------------
__global__ __launch_bounds__(256) void prep_kernel(const float* __restrict__ x,
                                                   float* __restrict__ stats,
                                                   const float* __restrict__ qkv_w,
                                                   const float* __restrict__ proj_w,
                                                   unsigned short* __restrict__ wbf) {
    int tid = threadIdx.x;
    if (blockIdx.x >= 256) {
        int gid = (blockIdx.x - 256) * 256 + tid;
        for (int i = gid; i < 65536; i += 128 * 256) {
            float4 v = (i < 49152) ? ((const float4*)qkv_w)[i]
                                   : ((const float4*)proj_w)[i - 49152];
            *(uint2*)&wbf[(size_t)i * 4] = make_uint2(pk2bf(v.x, v.y), pk2bf(v.z, v.w));
        }
        return;
    }
    int bg = blockIdx.x >> 2, part = blockIdx.x & 3;
    const float4* xp4 = (const float4*)(x + (size_t)bg * (kCg * kT)) + part * 4096;
    float s = 0.f, q = 0.f;
    #pragma unroll 4
    for (int i = 0; i < 16; ++i) {
        float4 v = xp4[tid + i * 256];
        s += v.x + v.y + v.z + v.w;
        q += v.x * v.x + v.y * v.y + v.z * v.z + v.w * v.w;
    }
    #pragma unroll
    for (int off = 32; off > 0; off >>= 1) {
        s += __shfl_down(s, off);
        q += __shfl_down(q, off);
    }
    __shared__ float rs[4], rq[4];
    int wid = tid >> 6, lane = tid & 63;
    if (lane == 0) { rs[wid] = s; rq[wid] = q; }
    __syncthreads();
    if (tid == 0) {
        float S = rs[0] + rs[1] + rs[2] + rs[3];
        float Q = rq[0] + rq[1] + rq[2] + rq[3];
        stats[blockIdx.x * 2 + 0] = S;
        stats[blockIdx.x * 2 + 1] = Q;
    }
}

// ---------------------------------------------------------------------------
// Kernel 2 (R21): apply GroupNorm affine + transpose -> normT[b][t][c] bf16.
// ---------------------------------------------------------------------------
__global__ __launch_bounds__(256) void gn_apply_t_kernel(const float* __restrict__ x,
                                                         const float* __restrict__ stats,
                                                         const float* __restrict__ w,
                                                         const float* __restrict__ bias,
                                                         unsigned short* __restrict__ normT) {
    __shared__ float Ls[64][65];
    int t0 = blockIdx.x * 64;
    int c0 = blockIdx.y * 64;
    int b  = blockIdx.z;
    int tid = threadIdx.x;
    const float invN = 1.0f / (float)(kCg * kT);
    #pragma unroll
    for (int p = 0; p < 4; ++p) {
        int idx = tid + p * 256;
        int cl = idx >> 4, t4 = idx & 15;
        int c = c0 + cl;
        int bg = b * kG + (c >> 4);
        float S = 0.f, Q = 0.f;
        #pragma unroll
        for (int pr = 0; pr < 4; ++pr) {
            S += stats[(bg * 4 + pr) * 2 + 0];
            Q += stats[(bg * 4 + pr) * 2 + 1];
        }
        float mean = S * invN;
        float rstd = rsqrtf(Q * invN - mean * mean + kEps);
        float sw = w[c] * rstd;
        float sb = bias[c] - mean * sw;
        float4 v = *(const float4*)&x[((size_t)b * kC + c) * kT + t0 + t4 * 4];
        Ls[t4 * 4 + 0][cl] = v.x * sw + sb;
        Ls[t4 * 4 + 1][cl] = v.y * sw + sb;
        Ls[t4 * 4 + 2][cl] = v.z * sw + sb;
        Ls[t4 * 4 + 3][cl] = v.w * sw + sb;
    }
    __syncthreads();
    {
        int row = tid >> 2, cq = (tid & 3) * 16;
        unsigned tmp[8];
        #pragma unroll
        for (int i = 0; i < 8; ++i)
            tmp[i] = pk2bf(Ls[row][cq + 2 * i], Ls[row][cq + 2 * i + 1]);
        uint4* dst = (uint4*)&normT[((size_t)b * kT + t0 + row) * kC + c0 + cq];
        dst[0] = make_uint4(tmp[0], tmp[1], tmp[2], tmp[3]);
        dst[1] = make_uint4(tmp[4], tmp[5], tmp[6], tmp[7]);
    }
}

// ---------------------------------------------------------------------------
// Kernel 3: qkv GEMM (bf16 MFMA), R23 structure: global_load_lds staging,
// linear LDS + rule-#21 XOR swizzle pair, t-tile 256.
//   q/k out: frag[tb=t/32][ks=c/16][hi=(c/8)&1][ln=t&31][e=c&7]
//   v out:   frag[sg=s/16][hi=(s/8)&1][c][e=s&7]
// ---------------------------------------------------------------------------
__global__ __launch_bounds__(256) void qkv_gemm_kernel(const unsigned short* __restrict__ wbf,
                                                       const float* __restrict__ qkv_b,
                                                       const unsigned short* __restrict__ normT,
                                                       unsigned short* __restrict__ qTg,
                                                       unsigned short* __restrict__ kTg,
                                                       unsigned short* __restrict__ vCg) {
    constexpr int LDK = 72;    // epilogue pitch only
    constexpr int LDV = 264;   // epilogue v pitch
    __shared__ __align__(16) unsigned short U[(64 + 256) * 64];
    unsigned short* As = U;
    unsigned short* Bs = U + 64 * 64;
    unsigned short* Ep = U;   // epilogue staging overlay

    int t0 = blockIdx.x * 256;
    int m0 = blockIdx.y * 64;
    int b  = blockIdx.z;
    const unsigned short* Ab = wbf + (size_t)m0 * kC;
    const unsigned short* Bb = normT + (size_t)b * kT * kC;

    int tid = threadIdx.x;
    int wave = tid >> 6, lane = tid & 63;
    int ln15 = lane & 15, quad = lane >> 4;
    int wm = wave >> 1, wt = wave & 1;
    int lrow = lane >> 3, lseg = lane & 7;

    f32x4 acc[2][8] = {};

    for (int k0 = 0; k0 < kC; k0 += 64) {
        __syncthreads();
        #pragma unroll
        for (int i = 0; i < 2; ++i) {
            int row = wave * 16 + i * 8 + lrow;
            int sseg = lseg ^ (row & 7);
            llds16(&Ab[(size_t)row * kC + k0 + sseg * 8], As + (wave * 2 + i) * 512);
        }
        #pragma unroll
        for (int i = 0; i < 8; ++i) {
            int row = wave * 64 + i * 8 + lrow;
            int sseg = lseg ^ (row & 7);
            llds16(&Bb[(size_t)(t0 + row) * kC + k0 + sseg * 8], Bs + (wave * 8 + i) * 512);
        }
        __syncthreads();   // drains vmcnt(0): all DMA fills visible
        #pragma unroll
        for (int ks = 0; ks < 2; ++ks) {
            bf16x8 af[2], bf[8];
            #pragma unroll
            for (int i = 0; i < 2; ++i) {
                int r = wm * 32 + i * 16 + ln15;
                af[i] = *(bf16x8*)&As[r * 64 + (((ks * 4 + quad) ^ (r & 7)) * 8)];
            }
            #pragma unroll
            for (int j = 0; j < 8; ++j) {
                int t = wt * 128 + j * 16 + ln15;
                bf[j] = *(bf16x8*)&Bs[t * 64 + (((ks * 4 + quad) ^ (t & 7)) * 8)];
            }
            #pragma unroll
            for (int i = 0; i < 2; ++i)
                #pragma unroll
                for (int j = 0; j < 8; ++j)
                    acc[i][j] = __builtin_amdgcn_mfma_f32_16x16x32_bf16(
                        af[i], bf[j], acc[i][j], 0, 0, 0);
        }
    }

    int type = (m0 % 192) / 64;   // 0=q, 1=k, 2=v
    int h = m0 / 192;
    int bh = b * kH + h;
    __syncthreads();   // all MFMA reads of As/Bs done; overlay as staging
    #pragma unroll
    for (int i = 0; i < 2; ++i) {
        float4 bv = *(const float4*)&qkv_b[m0 + wm * 32 + i * 16 + quad * 4];
        const float* bp = (const float*)&bv;
        #pragma unroll
        for (int j = 0; j < 8; ++j) {
            int tl = wt * 128 + j * 16 + ln15;
            int c = wm * 32 + i * 16 + quad * 4;
            float v0 = acc[i][j][0] + bp[0];
            float v1 = acc[i][j][1] + bp[1];
            float v2 = acc[i][j][2] + bp[2];
            float v3 = acc[i][j][3] + bp[3];
            if (type == 0) {
                v0 *= kQScale; v1 *= kQScale; v2 *= kQScale; v3 *= kQScale;
            }
            if (type != 2) {
                *(uint2*)&Ep[tl * LDK + c] = make_uint2(pk2bf(v0, v1), pk2bf(v2, v3));
            } else {
                Ep[(c + 0) * LDV + tl] = f2bf(v0);
                Ep[(c + 1) * LDV + tl] = f2bf(v1);
                Ep[(c + 2) * LDV + tl] = f2bf(v2);
                Ep[(c + 3) * LDV + tl] = f2bf(v3);
            }
        }
    }
    __syncthreads();
    if (type != 2) {
        unsigned short* base = ((type == 0) ? qTg : kTg) + (size_t)bh * (kT * kCh);
        #pragma unroll
        for (int p = 0; p < 8; ++p) {
            int f = tid + p * 256;
            int ln = f & 31, hif = (f >> 5) & 1, ks = (f >> 6) & 3, tb = f >> 8;
            *(uint4*)&base[((t0 >> 5) + tb) * 2048 + ks * 512 + hif * 256 + ln * 8] =
                *(uint4*)&Ep[(tb * 32 + ln) * LDK + ks * 16 + hif * 8];
        }
    } else {
        unsigned short* base = vCg + (size_t)bh * (kT * kCh);
        #pragma unroll
        for (int p = 0; p < 8; ++p) {
            int f = tid + p * 256;
            int c = f & 63, hif = (f >> 6) & 1, sg = f >> 7;
            *(uint4*)&base[((t0 >> 4) + sg) * 1024 + hif * 512 + c * 8] =
                *(uint4*)&Ep[c * LDV + sg * 16 + hif * 8];
        }
    }
}

// ---------------------------------------------------------------------------
// Kernel 4: REGISTER-ONLY MFMA flash attention (R16 body). R24 DIAGNOSTIC:
// split into TWO half-dispatches (8 bh each, 256 blocks) so non-attn
// kernels >= ~40us become visible in the top-5 table (which 15 identical
// 77us attn instances otherwise saturate). Known cost: 1 block/CU per
// dispatch (R19: +6-8% on attn). Revert the split next round.
// C-layout: col t=lane&31, row s=(reg&3)+8*(reg>>2)+4*hi (m74/m101).
// ---------------------------------------------------------------------------
__global__ __launch_bounds__(256, 2) void attn_mfma_kernel(const unsigned short* __restrict__ qTg,
                                                           const unsigned short* __restrict__ kTg,
                                                           const unsigned short* __restrict__ vCg,
                                                           unsigned short* __restrict__ attnT,
                                                           int half) {
    __shared__ float Ored[2][2][32][64];   // [tc][chunk][acc elem][lane]
    __shared__ float Lred[2][2][64];

    // XCD-chunked remap within this half's 256 work items (bijective).
    int lid = blockIdx.y * 16 + blockIdx.x;
    int wl  = half * 256 + (lid & 7) * 32 + (lid >> 3);
    int bh  = wl >> 5;
    int t0  = (wl & 31) * 128;
    int b = bh >> 2, h = bh & 3;

    int tid = threadIdx.x;
    int wave = tid >> 6, lane = tid & 63;
    int ln31 = lane & 31, hi = lane >> 5;
    int tc = wave & 1;    // which 64-t span of the block's 128 t
    int sh = wave >> 1;   // which 2048-s half of the KV range

    const unsigned short* qb = qTg + (size_t)bh * (kT * kCh);
    const unsigned short* kb = kTg + (size_t)bh * (kT * kCh);
    const unsigned short* vb = vCg + (size_t)bh * (kT * kCh);

    bf16x8 qA[4], qB[4];
    {
        const unsigned short* qp = qb + ((size_t)(t0 >> 5) + tc * 2) * 2048 + hi * 256 + ln31 * 8;
        #pragma unroll
        for (int ks = 0; ks < 4; ++ks) {
            qA[ks] = *(const bf16x8*)(qp + ks * 512);
            qB[ks] = *(const bf16x8*)(qp + 2048 + ks * 512);
        }
    }

    const unsigned short* kbase = kb + (size_t)sh * 131072 + hi * 256 + ln31 * 8;
    const unsigned short* vbase = vb + (size_t)sh * 131072 + hi * 512 + ln31 * 8;

    float lA = 0.f, lB = 0.f;
    f32x16 oA0 = {}, oA1 = {}, oB0 = {}, oB1 = {};

    auto loadKV = [&](bf16x8* kf, bf16x8* vf, int idx) {
        const unsigned short* kp = kbase + (size_t)idx * 2048;
        const unsigned short* vp = vbase + (size_t)idx * 2048;
        kf[0] = *(const bf16x8*)(kp);
        kf[1] = *(const bf16x8*)(kp + 512);
        kf[2] = *(const bf16x8*)(kp + 1024);
        kf[3] = *(const bf16x8*)(kp + 1536);
        vf[0] = *(const bf16x8*)(vp);           // ct=0, s-chunk 0
        vf[1] = *(const bf16x8*)(vp + 256);     // ct=1, s-chunk 0
        vf[2] = *(const bf16x8*)(vp + 1024);    // ct=0, s-chunk 1
        vf[3] = *(const bf16x8*)(vp + 1280);    // ct=1, s-chunk 1
    };

    auto softmax_pack = [&](const f32x16& s, float& l, bf16x8& f0, bf16x8& f1) {
        unsigned u00, u01, u10, u11, u20, u21, u30, u31;
        {
            float p0 = __builtin_amdgcn_exp2f(s[0]);
            float p1 = __builtin_amdgcn_exp2f(s[1]);
            float p2 = __builtin_amdgcn_exp2f(s[2]);
            float p3 = __builtin_amdgcn_exp2f(s[3]);
            l += (p0 + p1) + (p2 + p3);
            u00 = pk2bf_trunc(p0, p1); u01 = pk2bf_trunc(p2, p3);
        }
        {
            float p0 = __builtin_amdgcn_exp2f(s[4]);
            float p1 = __builtin_amdgcn_exp2f(s[5]);
            float p2 = __builtin_amdgcn_exp2f(s[6]);
            float p3 = __builtin_amdgcn_exp2f(s[7]);
            l += (p0 + p1) + (p2 + p3);
            u10 = pk2bf_trunc(p0, p1); u11 = pk2bf_trunc(p2, p3);
        }
        {
            float p0 = __builtin_amdgcn_exp2f(s[8]);
            float p1 = __builtin_amdgcn_exp2f(s[9]);
            float p2 = __builtin_amdgcn_exp2f(s[10]);
            float p3 = __builtin_amdgcn_exp2f(s[11]);
            l += (p0 + p1) + (p2 + p3);
            u20 = pk2bf_trunc(p0, p1); u21 = pk2bf_trunc(p2, p3);
        }
        {
            float p0 = __builtin_amdgcn_exp2f(s[12]);
            float p1 = __builtin_amdgcn_exp2f(s[13]);
            float p2 = __builtin_amdgcn_exp2f(s[14]);
            float p3 = __builtin_amdgcn_exp2f(s[15]);
            l += (p0 + p1) + (p2 + p3);
            u30 = pk2bf_trunc(p0, p1); u31 = pk2bf_trunc(p2, p3);
        }
        pls32(u00, u10); pls32(u01, u11);
        pls32(u20, u30); pls32(u21, u31);
        PunP P0, P1;
        P0.u = make_uint4(u00, u01, u10, u11);
        P1.u = make_uint4(u20, u21, u30, u31);
        f0 = P0.f; f1 = P1.f;
    };

    auto computeTile = [&](const bf16x8* kf, const bf16x8* vf) {
        f32x16 sA = {}, sB = {};
        __builtin_amdgcn_s_setprio(1);
        #pragma unroll
        for (int ks = 0; ks < 4; ++ks) {
            sA = __builtin_amdgcn_mfma_f32_32x32x16_bf16(kf[ks], qA[ks], sA, 0, 0, 0);
            sB = __builtin_amdgcn_mfma_f32_32x32x16_bf16(kf[ks], qB[ks], sB, 0, 0, 0);
        }
        __builtin_amdgcn_s_setprio(0);
        bf16x8 FA0, FA1, FB0, FB1;
        softmax_pack(sA, lA, FA0, FA1);
        softmax_pack(sB, lB, FB0, FB1);
        __builtin_amdgcn_s_setprio(1);
        oA0 = __builtin_amdgcn_mfma_f32_32x32x16_bf16(vf[0], FA0, oA0, 0, 0, 0);
        oA1 = __builtin_amdgcn_mfma_f32_32x32x16_bf16(vf[1], FA0, oA1, 0, 0, 0);
        oB0 = __builtin_amdgcn_mfma_f32_32x32x16_bf16(vf[0], FB0, oB0, 0, 0, 0);
        oB1 = __builtin_amdgcn_mfma_f32_32x32x16_bf16(vf[1], FB0, oB1, 0, 0, 0);
        oA0 = __builtin_amdgcn_mfma_f32_32x32x16_bf16(vf[2], FA1, oA0, 0, 0, 0);
        oA1 = __builtin_amdgcn_mfma_f32_32x32x16_bf16(vf[3], FA1, oA1, 0, 0, 0);
        oB0 = __builtin_amdgcn_mfma_f32_32x32x16_bf16(vf[2], FB1, oB0, 0, 0, 0);
        oB1 = __builtin_amdgcn_mfma_f32_32x32x16_bf16(vf[3], FB1, oB1, 0, 0, 0);
        __builtin_amdgcn_s_setprio(0);
    };

    bf16x8 kX[4], vX[4], kY[4], vY[4];
    loadKV(kX, vX, 0);
    __builtin_amdgcn_sched_barrier(0);
    #pragma unroll 1
    for (int it = 0; it < 64; it += 2) {
        loadKV(kY, vY, it + 1);              // prefetch next tile
        __builtin_amdgcn_sched_barrier(0);   // PIN: loads may not sink below
        computeTile(kX, vX);
        loadKV(kX, vX, (it + 2) & 63);       // wrap-load on last trip (unused)
        __builtin_amdgcn_sched_barrier(0);   // PIN
        computeTile(kY, vY);
    }

    lA += __shfl_xor(lA, 32);
    lB += __shfl_xor(lB, 32);

    if (sh == 1) {
        #pragma unroll
        for (int e = 0; e < 16; ++e) {
            Ored[tc][0][e][lane]      = oA0[e];
            Ored[tc][0][16 + e][lane] = oA1[e];
            Ored[tc][1][e][lane]      = oB0[e];
            Ored[tc][1][16 + e][lane] = oB1[e];
        }
        Lred[tc][0][lane] = lA;
        Lred[tc][1][lane] = lB;
    }
    __syncthreads();
    if (sh == 0) {
        #pragma unroll
        for (int e = 0; e < 16; ++e) {
            oA0[e] += Ored[tc][0][e][lane];
            oA1[e] += Ored[tc][0][16 + e][lane];
            oB0[e] += Ored[tc][1][e][lane];
            oB1[e] += Ored[tc][1][16 + e][lane];
        }
        lA += Lred[tc][0][lane];
        lB += Lred[tc][1][lane];
        #pragma unroll
        for (int ch = 0; ch < 2; ++ch) {
            float linv = 1.0f / (ch ? lB : lA);
            int t = t0 + tc * 64 + ch * 32 + ln31;
            #pragma unroll
            for (int ct = 0; ct < 2; ++ct) {
                const f32x16& ao = ch ? (ct ? oB1 : oB0) : (ct ? oA1 : oA0);
                #pragma unroll
                for (int g = 0; g < 4; ++g) {
                    int c = h * kCh + ct * 32 + 8 * g + 4 * hi;
                    float v0 = ao[4 * g + 0] * linv;
                    float v1 = ao[4 * g + 1] * linv;
                    float v2 = ao[4 * g + 2] * linv;
                    float v3 = ao[4 * g + 3] * linv;
                    *(uint2*)&attnT[((size_t)b * kT + t) * kC + c] =
                        make_uint2(pk2bf(v0, v1), pk2bf(v2, v3));
                }
            }
        }
    }
}

// ---------------------------------------------------------------------------
// Kernel 5: proj GEMM + bias + residual -> fp32 (R23 structure).
// ---------------------------------------------------------------------------
__global__ __launch_bounds__(256) void proj_gemm_kernel(const unsigned short* __restrict__ wpbf,
                                                        const float* __restrict__ proj_b,
                                                        const unsigned short* __restrict__ attnT,
                                                        const float* __restrict__ x,
                                                        float* __restrict__ out) {
    __shared__ __align__(16) unsigned short U[(64 + 256) * 64];
    unsigned short* As = U;
    unsigned short* Bs = U + 64 * 64;

    int t0 = blockIdx.x * 256;
    int m0 = blockIdx.y * 64;
    int b  = blockIdx.z;
    const unsigned short* Ab = wpbf + (size_t)m0 * kC;
    const unsigned short* Bb = attnT + (size_t)b * kT * kC;

    int tid = threadIdx.x;
    int wave = tid >> 6, lane = tid & 63;
    int ln15 = lane & 15, quad = lane >> 4;
    int wm = wave >> 1, wt = wave & 1;
    int lrow = lane >> 3, lseg = lane & 7;

    f32x4 acc[2][8] = {};

    for (int k0 = 0; k0 < kC; k0 += 64) {
        __syncthreads();
        #pragma unroll
        for (int i = 0; i < 2; ++i) {
            int row = wave * 16 + i * 8 + lrow;
            int sseg = lseg ^ (row & 7);
            llds16(&Ab[(size_t)row * kC + k0 + sseg * 8], As + (wave * 2 + i) * 512);
        }
        #pragma unroll
        for (int i = 0; i < 8; ++i) {
            int row = wave * 64 + i * 8 + lrow;
            int sseg = lseg ^ (row & 7);
            llds16(&Bb[(size_t)(t0 + row) * kC + k0 + sseg * 8], Bs + (wave * 8 + i) * 512);
        }
        __syncthreads();
        #pragma unroll
        for (int ks = 0; ks < 2; ++ks) {
            bf16x8 af[2], bf[8];
            #pragma unroll
            for (int i = 0; i < 2; ++i) {
                int r = wm * 32 + i * 16 + ln15;
                af[i] = *(bf16x8*)&As[r * 64 + (((ks * 4 + quad) ^ (r & 7)) * 8)];
            }
            #pragma unroll
            for (int j = 0; j < 8; ++j) {
                int t = wt * 128 + j * 16 + ln15;
                bf[j] = *(bf16x8*)&Bs[t * 64 + (((ks * 4 + quad) ^ (t & 7)) * 8)];
            }
            #pragma unroll
            for (int i = 0; i < 2; ++i)
                #pragma unroll
                for (int j = 0; j < 8; ++j)
                    acc[i][j] = __builtin_amdgcn_mfma_f32_16x16x32_bf16(
                        af[i], bf[j], acc[i][j], 0, 0, 0);
        }
    }

    #pragma unroll
    for (int i = 0; i < 2; ++i) {
        float4 bv = *(const float4*)&proj_b[m0 + wm * 32 + i * 16 + quad * 4];
        const float* bp = (const float*)&bv;
        #pragma unroll
        for (int j = 0; j < 8; ++j) {
            int t = t0 + wt * 128 + j * 16 + ln15;
            int mbase = m0 + wm * 32 + i * 16 + quad * 4;
            #pragma unroll
            for (int r = 0; r < 4; ++r) {
                size_t off = ((size_t)b * kC + mbase + r) * kT + t;
                out[off] = acc[i][j][r] + bp[r] + x[off];
            }
        }
    }
}

// ---------------------------------------------------------------------------
extern "C" void kernel_launch(void* const* d_in, const int* in_sizes, int n_in,
                              void* d_out, int out_size, void* d_ws, size_t ws_size,
                              hipStream_t stream) {
    const float* x      = (const float*)d_in[0];
    const float* norm_w = (const float*)d_in[1];
    const float* norm_b = (const float*)d_in[2];
    const float* qkv_w  = (const float*)d_in[3];
    const float* qkv_b  = (const float*)d_in[4];
    const float* proj_w = (const float*)d_in[5];
    const float* proj_b = (const float*)d_in[6];
    float* out = (float*)d_out;

    // Workspace: stats fp32[512] (4 partials x 64 groups x {S,Q}) |
    // bf16: normT[4.19M] wbf[262144] qT kT vC attnT[4.19M each]
    float* stats = (float*)d_ws;
    unsigned short* wsbf  = (unsigned short*)((float*)d_ws + 512);
    unsigned short* normT = wsbf;
    unsigned short* wbf   = normT + (size_t)kB * kT * kC;
    unsigned short* qTp   = wbf + 262144;
    unsigned short* kTp   = qTp + (size_t)kB * kH * kT * kCh;
    unsigned short* vCp   = kTp + (size_t)kB * kH * kT * kCh;
    unsigned short* attnT = vCp + (size_t)kB * kH * kT * kCh;
    unsigned short* wpbf  = wbf + 196608;

    prep_kernel<<<384, 256, 0, stream>>>(x, stats, qkv_w, proj_w, wbf);
    gn_apply_t_kernel<<<dim3(kT / 64, kC / 64, kB), 256, 0, stream>>>(
        x, stats, norm_w, norm_b, normT);
    qkv_gemm_kernel<<<dim3(kT / 256, 12, kB), 256, 0, stream>>>(
        wbf, qkv_b, normT, qTp, kTp, vCp);
    attn_mfma_kernel<<<dim3(16, 16), 256, 0, stream>>>(qTp, kTp, vCp, attnT, 0);
    attn_mfma_kernel<<<dim3(16, 16), 256, 0, stream>>>(qTp, kTp, vCp, attnT, 1);
    proj_gemm_kernel<<<dim3(kT / 256, kC / 64, kB), 256, 0, stream>>>(
        wpbf, proj_b, attnT, x, out);
}

// Round 13
// 175.621 us; speedup vs baseline: 1.0328x; 1.0328x over previous
//
#include <hip/hip_runtime.h>

// Problem constants (B=4, C=256, H=W=64 -> T=4096)
constexpr int kB  = 4;
constexpr int kC  = 256;
constexpr int kT  = 4096;
constexpr int kG  = 16;
constexpr int kCg = kC / kG;   // 16 channels per group
constexpr int kH  = 4;         // heads
constexpr int kCh = kC / kH;   // 64 channels per head
constexpr float kEps = 1e-5f;
// q scale: 1/8 (=scale^2) folded with log2(e) for exp2-domain softmax
constexpr float kQScale = 0.125f * 1.4426950408889634f;

typedef short bf16x8 __attribute__((ext_vector_type(8)));
typedef float f32x4  __attribute__((ext_vector_type(4)));
typedef float f32x16 __attribute__((ext_vector_type(16)));

union PunP { uint4 u; bf16x8 f; };

__device__ inline unsigned short f2bf(float f) {
    union { float f; unsigned u; } v; v.f = f;
    unsigned r = v.u + 0x7fffu + ((v.u >> 16) & 1u);   // RNE
    return (unsigned short)(r >> 16);
}
__device__ inline unsigned pk2bf(float a, float b) {
    return (unsigned)f2bf(a) | ((unsigned)f2bf(b) << 16);
}
// truncating pack of two fp32 -> bf16x2 in ONE v_perm_b32 (high halves)
__device__ inline unsigned pk2bf_trunc(float a, float b) {
    return __builtin_amdgcn_perm(__float_as_uint(b), __float_as_uint(a), 0x07060302u);
}
// v_permlane32_swap_b32: a[32:63] <-> b[0:31].
__device__ inline void pls32(unsigned& a, unsigned& b) {
    __asm__("v_permlane32_swap_b32 %0, %1" : "+v"(a), "+v"(b));
}
// async global->LDS DMA, 16B per lane: LDS dest = uniform base + lane*16.
__device__ inline void llds16(const unsigned short* g, unsigned short* l) {
    __builtin_amdgcn_global_load_lds(
        (const __attribute__((address_space(1))) unsigned int*)(g),
        (__attribute__((address_space(3))) unsigned int*)(l), 16, 0, 0);
}

// ---------------------------------------------------------------------------
// Kernel 1 (R21): GroupNorm statistics + weight fp32->bf16 convert.
// Partial sums to DISJOINT slots stats[(bg*4+part)*2] (no atomics, no
// memset). 256 stat blocks + 128 convert blocks.
// ---------------------------------------------------------------------------
__global__ __launch_bounds__(256) void prep_kernel(const float* __restrict__ x,
                                                   float* __restrict__ stats,
                                                   const float* __restrict__ qkv_w,
                                                   const float* __restrict__ proj_w,
                                                   unsigned short* __restrict__ wbf) {
    int tid = threadIdx.x;
    if (blockIdx.x >= 256) {
        int gid = (blockIdx.x - 256) * 256 + tid;
        for (int i = gid; i < 65536; i += 128 * 256) {
            float4 v = (i < 49152) ? ((const float4*)qkv_w)[i]
                                   : ((const float4*)proj_w)[i - 49152];
            *(uint2*)&wbf[(size_t)i * 4] = make_uint2(pk2bf(v.x, v.y), pk2bf(v.z, v.w));
        }
        return;
    }
    int bg = blockIdx.x >> 2, part = blockIdx.x & 3;
    const float4* xp4 = (const float4*)(x + (size_t)bg * (kCg * kT)) + part * 4096;
    float s = 0.f, q = 0.f;
    #pragma unroll 4
    for (int i = 0; i < 16; ++i) {
        float4 v = xp4[tid + i * 256];
        s += v.x + v.y + v.z + v.w;
        q += v.x * v.x + v.y * v.y + v.z * v.z + v.w * v.w;
    }
    #pragma unroll
    for (int off = 32; off > 0; off >>= 1) {
        s += __shfl_down(s, off);
        q += __shfl_down(q, off);
    }
    __shared__ float rs[4], rq[4];
    int wid = tid >> 6, lane = tid & 63;
    if (lane == 0) { rs[wid] = s; rq[wid] = q; }
    __syncthreads();
    if (tid == 0) {
        float S = rs[0] + rs[1] + rs[2] + rs[3];
        float Q = rq[0] + rq[1] + rq[2] + rq[3];
        stats[blockIdx.x * 2 + 0] = S;
        stats[blockIdx.x * 2 + 1] = Q;
    }
}

// ---------------------------------------------------------------------------
// Kernel 2 (R21): apply GroupNorm affine + transpose -> normT[b][t][c] bf16.
// ---------------------------------------------------------------------------
__global__ __launch_bounds__(256) void gn_apply_t_kernel(const float* __restrict__ x,
                                                         const float* __restrict__ stats,
                                                         const float* __restrict__ w,
                                                         const float* __restrict__ bias,
                                                         unsigned short* __restrict__ normT) {
    __shared__ float Ls[64][65];
    int t0 = blockIdx.x * 64;
    int c0 = blockIdx.y * 64;
    int b  = blockIdx.z;
    int tid = threadIdx.x;
    const float invN = 1.0f / (float)(kCg * kT);
    #pragma unroll
    for (int p = 0; p < 4; ++p) {
        int idx = tid + p * 256;
        int cl = idx >> 4, t4 = idx & 15;
        int c = c0 + cl;
        int bg = b * kG + (c >> 4);
        float S = 0.f, Q = 0.f;
        #pragma unroll
        for (int pr = 0; pr < 4; ++pr) {
            S += stats[(bg * 4 + pr) * 2 + 0];
            Q += stats[(bg * 4 + pr) * 2 + 1];
        }
        float mean = S * invN;
        float rstd = rsqrtf(Q * invN - mean * mean + kEps);
        float sw = w[c] * rstd;
        float sb = bias[c] - mean * sw;
        float4 v = *(const float4*)&x[((size_t)b * kC + c) * kT + t0 + t4 * 4];
        Ls[t4 * 4 + 0][cl] = v.x * sw + sb;
        Ls[t4 * 4 + 1][cl] = v.y * sw + sb;
        Ls[t4 * 4 + 2][cl] = v.z * sw + sb;
        Ls[t4 * 4 + 3][cl] = v.w * sw + sb;
    }
    __syncthreads();
    {
        int row = tid >> 2, cq = (tid & 3) * 16;
        unsigned tmp[8];
        #pragma unroll
        for (int i = 0; i < 8; ++i)
            tmp[i] = pk2bf(Ls[row][cq + 2 * i], Ls[row][cq + 2 * i + 1]);
        uint4* dst = (uint4*)&normT[((size_t)b * kT + t0 + row) * kC + c0 + cq];
        dst[0] = make_uint4(tmp[0], tmp[1], tmp[2], tmp[3]);
        dst[1] = make_uint4(tmp[4], tmp[5], tmp[6], tmp[7]);
    }
}

// ---------------------------------------------------------------------------
// Kernel 3: qkv GEMM (bf16 MFMA), R23 structure (global_load_lds staging,
// linear LDS + rule-#21 XOR swizzle pair, t-tile 256). R25: bijective
// XCD-chunked remap — the 12 m-tiles sharing one B-tile (t,b) land on the
// same XCD, so B is fetched once per XCD and re-read from its private L2.
//   q/k out: frag[tb=t/32][ks=c/16][hi=(c/8)&1][ln=t&31][e=c&7]
//   v out:   frag[sg=s/16][hi=(s/8)&1][c][e=s&7]
// ---------------------------------------------------------------------------
__global__ __launch_bounds__(256) void qkv_gemm_kernel(const unsigned short* __restrict__ wbf,
                                                       const float* __restrict__ qkv_b,
                                                       const unsigned short* __restrict__ normT,
                                                       unsigned short* __restrict__ qTg,
                                                       unsigned short* __restrict__ kTg,
                                                       unsigned short* __restrict__ vCg) {
    constexpr int LDK = 72;    // epilogue pitch only
    constexpr int LDV = 264;   // epilogue v pitch
    __shared__ __align__(16) unsigned short U[(64 + 256) * 64];
    unsigned short* As = U;
    unsigned short* Bs = U + 64 * 64;
    unsigned short* Ep = U;   // epilogue staging overlay

    // XCD remap: f in [0,768); xcd gets 96 consecutive work items =
    // 8 (t,b) groups x 12 m. Bijective (768 = 8*96).
    int f = blockIdx.x + 16 * (blockIdx.y + 12 * blockIdx.z);
    int xcd = f & 7, idx = f >> 3;
    int g = idx / 12, m = idx - g * 12;
    int tb = xcd * 8 + g;
    int t0 = (tb & 15) * 256;
    int b  = tb >> 4;
    int m0 = m * 64;
    const unsigned short* Ab = wbf + (size_t)m0 * kC;
    const unsigned short* Bb = normT + (size_t)b * kT * kC;

    int tid = threadIdx.x;
    int wave = tid >> 6, lane = tid & 63;
    int ln15 = lane & 15, quad = lane >> 4;
    int wm = wave >> 1, wt = wave & 1;
    int lrow = lane >> 3, lseg = lane & 7;

    f32x4 acc[2][8] = {};

    for (int k0 = 0; k0 < kC; k0 += 64) {
        __syncthreads();
        #pragma unroll
        for (int i = 0; i < 2; ++i) {
            int row = wave * 16 + i * 8 + lrow;
            int sseg = lseg ^ (row & 7);
            llds16(&Ab[(size_t)row * kC + k0 + sseg * 8], As + (wave * 2 + i) * 512);
        }
        #pragma unroll
        for (int i = 0; i < 8; ++i) {
            int row = wave * 64 + i * 8 + lrow;
            int sseg = lseg ^ (row & 7);
            llds16(&Bb[(size_t)(t0 + row) * kC + k0 + sseg * 8], Bs + (wave * 8 + i) * 512);
        }
        __syncthreads();   // drains vmcnt(0): all DMA fills visible
        #pragma unroll
        for (int ks = 0; ks < 2; ++ks) {
            bf16x8 af[2], bf[8];
            #pragma unroll
            for (int i = 0; i < 2; ++i) {
                int r = wm * 32 + i * 16 + ln15;
                af[i] = *(bf16x8*)&As[r * 64 + (((ks * 4 + quad) ^ (r & 7)) * 8)];
            }
            #pragma unroll
            for (int j = 0; j < 8; ++j) {
                int t = wt * 128 + j * 16 + ln15;
                bf[j] = *(bf16x8*)&Bs[t * 64 + (((ks * 4 + quad) ^ (t & 7)) * 8)];
            }
            #pragma unroll
            for (int i = 0; i < 2; ++i)
                #pragma unroll
                for (int j = 0; j < 8; ++j)
                    acc[i][j] = __builtin_amdgcn_mfma_f32_16x16x32_bf16(
                        af[i], bf[j], acc[i][j], 0, 0, 0);
        }
    }

    int type = (m0 % 192) / 64;   // 0=q, 1=k, 2=v
    int h = m0 / 192;
    int bh = b * kH + h;
    __syncthreads();   // all MFMA reads of As/Bs done; overlay as staging
    #pragma unroll
    for (int i = 0; i < 2; ++i) {
        float4 bv = *(const float4*)&qkv_b[m0 + wm * 32 + i * 16 + quad * 4];
        const float* bp = (const float*)&bv;
        #pragma unroll
        for (int j = 0; j < 8; ++j) {
            int tl = wt * 128 + j * 16 + ln15;
            int c = wm * 32 + i * 16 + quad * 4;
            float v0 = acc[i][j][0] + bp[0];
            float v1 = acc[i][j][1] + bp[1];
            float v2 = acc[i][j][2] + bp[2];
            float v3 = acc[i][j][3] + bp[3];
            if (type == 0) {
                v0 *= kQScale; v1 *= kQScale; v2 *= kQScale; v3 *= kQScale;
            }
            if (type != 2) {
                *(uint2*)&Ep[tl * LDK + c] = make_uint2(pk2bf(v0, v1), pk2bf(v2, v3));
            } else {
                Ep[(c + 0) * LDV + tl] = f2bf(v0);
                Ep[(c + 1) * LDV + tl] = f2bf(v1);
                Ep[(c + 2) * LDV + tl] = f2bf(v2);
                Ep[(c + 3) * LDV + tl] = f2bf(v3);
            }
        }
    }
    __syncthreads();
    if (type != 2) {
        unsigned short* base = ((type == 0) ? qTg : kTg) + (size_t)bh * (kT * kCh);
        #pragma unroll
        for (int p = 0; p < 8; ++p) {
            int ff = tid + p * 256;
            int ln = ff & 31, hif = (ff >> 5) & 1, ks = (ff >> 6) & 3, tbk = ff >> 8;
            *(uint4*)&base[((t0 >> 5) + tbk) * 2048 + ks * 512 + hif * 256 + ln * 8] =
                *(uint4*)&Ep[(tbk * 32 + ln) * LDK + ks * 16 + hif * 8];
        }
    } else {
        unsigned short* base = vCg + (size_t)bh * (kT * kCh);
        #pragma unroll
        for (int p = 0; p < 8; ++p) {
            int ff = tid + p * 256;
            int c = ff & 63, hif = (ff >> 6) & 1, sg = ff >> 7;
            *(uint4*)&base[((t0 >> 4) + sg) * 1024 + hif * 512 + c * 8] =
                *(uint4*)&Ep[c * LDV + sg * 16 + hif * 8];
        }
    }
}

// ---------------------------------------------------------------------------
// Kernel 4: REGISTER-ONLY MFMA flash attention (R16 config — best measured,
// 77.2us). R24 split reverted (diagnostic served its purpose: found the
// 43.5us harness workspace-fill in the timed region). attn parked.
// C-layout: col t=lane&31, row s=(reg&3)+8*(reg>>2)+4*hi (m74/m101).
// ---------------------------------------------------------------------------
__global__ __launch_bounds__(256, 2) void attn_mfma_kernel(const unsigned short* __restrict__ qTg,
                                                           const unsigned short* __restrict__ kTg,
                                                           const unsigned short* __restrict__ vCg,
                                                           unsigned short* __restrict__ attnT) {
    __shared__ float Ored[2][2][32][64];   // [tc][chunk][acc elem][lane]
    __shared__ float Lred[2][2][64];

    // XCD-chunked work remap: 512 blocks / 8 XCDs (bijective, 512 % 8 == 0).
    int lid = blockIdx.y * 32 + blockIdx.x;
    int wl  = (lid & 7) * 64 + (lid >> 3);
    int bh  = wl >> 5;
    int t0  = (wl & 31) * 128;
    int b = bh >> 2, h = bh & 3;

    int tid = threadIdx.x;
    int wave = tid >> 6, lane = tid & 63;
    int ln31 = lane & 31, hi = lane >> 5;
    int tc = wave & 1;    // which 64-t span of the block's 128 t
    int sh = wave >> 1;   // which 2048-s half of the KV range

    const unsigned short* qb = qTg + (size_t)bh * (kT * kCh);
    const unsigned short* kb = kTg + (size_t)bh * (kT * kCh);
    const unsigned short* vb = vCg + (size_t)bh * (kT * kCh);

    bf16x8 qA[4], qB[4];
    {
        const unsigned short* qp = qb + ((size_t)(t0 >> 5) + tc * 2) * 2048 + hi * 256 + ln31 * 8;
        #pragma unroll
        for (int ks = 0; ks < 4; ++ks) {
            qA[ks] = *(const bf16x8*)(qp + ks * 512);
            qB[ks] = *(const bf16x8*)(qp + 2048 + ks * 512);
        }
    }

    const unsigned short* kbase = kb + (size_t)sh * 131072 + hi * 256 + ln31 * 8;
    const unsigned short* vbase = vb + (size_t)sh * 131072 + hi * 512 + ln31 * 8;

    float lA = 0.f, lB = 0.f;
    f32x16 oA0 = {}, oA1 = {}, oB0 = {}, oB1 = {};

    auto loadKV = [&](bf16x8* kf, bf16x8* vf, int idx) {
        const unsigned short* kp = kbase + (size_t)idx * 2048;
        const unsigned short* vp = vbase + (size_t)idx * 2048;
        kf[0] = *(const bf16x8*)(kp);
        kf[1] = *(const bf16x8*)(kp + 512);
        kf[2] = *(const bf16x8*)(kp + 1024);
        kf[3] = *(const bf16x8*)(kp + 1536);
        vf[0] = *(const bf16x8*)(vp);           // ct=0, s-chunk 0
        vf[1] = *(const bf16x8*)(vp + 256);     // ct=1, s-chunk 0
        vf[2] = *(const bf16x8*)(vp + 1024);    // ct=0, s-chunk 1
        vf[3] = *(const bf16x8*)(vp + 1280);    // ct=1, s-chunk 1
    };

    auto softmax_pack = [&](const f32x16& s, float& l, bf16x8& f0, bf16x8& f1) {
        unsigned u00, u01, u10, u11, u20, u21, u30, u31;
        {
            float p0 = __builtin_amdgcn_exp2f(s[0]);
            float p1 = __builtin_amdgcn_exp2f(s[1]);
            float p2 = __builtin_amdgcn_exp2f(s[2]);
            float p3 = __builtin_amdgcn_exp2f(s[3]);
            l += (p0 + p1) + (p2 + p3);
            u00 = pk2bf_trunc(p0, p1); u01 = pk2bf_trunc(p2, p3);
        }
        {
            float p0 = __builtin_amdgcn_exp2f(s[4]);
            float p1 = __builtin_amdgcn_exp2f(s[5]);
            float p2 = __builtin_amdgcn_exp2f(s[6]);
            float p3 = __builtin_amdgcn_exp2f(s[7]);
            l += (p0 + p1) + (p2 + p3);
            u10 = pk2bf_trunc(p0, p1); u11 = pk2bf_trunc(p2, p3);
        }
        {
            float p0 = __builtin_amdgcn_exp2f(s[8]);
            float p1 = __builtin_amdgcn_exp2f(s[9]);
            float p2 = __builtin_amdgcn_exp2f(s[10]);
            float p3 = __builtin_amdgcn_exp2f(s[11]);
            l += (p0 + p1) + (p2 + p3);
            u20 = pk2bf_trunc(p0, p1); u21 = pk2bf_trunc(p2, p3);
        }
        {
            float p0 = __builtin_amdgcn_exp2f(s[12]);
            float p1 = __builtin_amdgcn_exp2f(s[13]);
            float p2 = __builtin_amdgcn_exp2f(s[14]);
            float p3 = __builtin_amdgcn_exp2f(s[15]);
            l += (p0 + p1) + (p2 + p3);
            u30 = pk2bf_trunc(p0, p1); u31 = pk2bf_trunc(p2, p3);
        }
        pls32(u00, u10); pls32(u01, u11);
        pls32(u20, u30); pls32(u21, u31);
        PunP P0, P1;
        P0.u = make_uint4(u00, u01, u10, u11);
        P1.u = make_uint4(u20, u21, u30, u31);
        f0 = P0.f; f1 = P1.f;
    };

    auto computeTile = [&](const bf16x8* kf, const bf16x8* vf) {
        f32x16 sA = {}, sB = {};
        __builtin_amdgcn_s_setprio(1);
        #pragma unroll
        for (int ks = 0; ks < 4; ++ks) {
            sA = __builtin_amdgcn_mfma_f32_32x32x16_bf16(kf[ks], qA[ks], sA, 0, 0, 0);
            sB = __builtin_amdgcn_mfma_f32_32x32x16_bf16(kf[ks], qB[ks], sB, 0, 0, 0);
        }
        __builtin_amdgcn_s_setprio(0);
        bf16x8 FA0, FA1, FB0, FB1;
        softmax_pack(sA, lA, FA0, FA1);
        softmax_pack(sB, lB, FB0, FB1);
        __builtin_amdgcn_s_setprio(1);
        oA0 = __builtin_amdgcn_mfma_f32_32x32x16_bf16(vf[0], FA0, oA0, 0, 0, 0);
        oA1 = __builtin_amdgcn_mfma_f32_32x32x16_bf16(vf[1], FA0, oA1, 0, 0, 0);
        oB0 = __builtin_amdgcn_mfma_f32_32x32x16_bf16(vf[0], FB0, oB0, 0, 0, 0);
        oB1 = __builtin_amdgcn_mfma_f32_32x32x16_bf16(vf[1], FB0, oB1, 0, 0, 0);
        oA0 = __builtin_amdgcn_mfma_f32_32x32x16_bf16(vf[2], FA1, oA0, 0, 0, 0);
        oA1 = __builtin_amdgcn_mfma_f32_32x32x16_bf16(vf[3], FA1, oA1, 0, 0, 0);
        oB0 = __builtin_amdgcn_mfma_f32_32x32x16_bf16(vf[2], FB1, oB0, 0, 0, 0);
        oB1 = __builtin_amdgcn_mfma_f32_32x32x16_bf16(vf[3], FB1, oB1, 0, 0, 0);
        __builtin_amdgcn_s_setprio(0);
    };

    bf16x8 kX[4], vX[4], kY[4], vY[4];
    loadKV(kX, vX, 0);
    __builtin_amdgcn_sched_barrier(0);
    #pragma unroll 1
    for (int it = 0; it < 64; it += 2) {
        loadKV(kY, vY, it + 1);              // prefetch next tile
        __builtin_amdgcn_sched_barrier(0);   // PIN: loads may not sink below
        computeTile(kX, vX);
        loadKV(kX, vX, (it + 2) & 63);       // wrap-load on last trip (unused)
        __builtin_amdgcn_sched_barrier(0);   // PIN
        computeTile(kY, vY);
    }

    lA += __shfl_xor(lA, 32);
    lB += __shfl_xor(lB, 32);

    if (sh == 1) {
        #pragma unroll
        for (int e = 0; e < 16; ++e) {
            Ored[tc][0][e][lane]      = oA0[e];
            Ored[tc][0][16 + e][lane] = oA1[e];
            Ored[tc][1][e][lane]      = oB0[e];
            Ored[tc][1][16 + e][lane] = oB1[e];
        }
        Lred[tc][0][lane] = lA;
        Lred[tc][1][lane] = lB;
    }
    __syncthreads();
    if (sh == 0) {
        #pragma unroll
        for (int e = 0; e < 16; ++e) {
            oA0[e] += Ored[tc][0][e][lane];
            oA1[e] += Ored[tc][0][16 + e][lane];
            oB0[e] += Ored[tc][1][e][lane];
            oB1[e] += Ored[tc][1][16 + e][lane];
        }
        lA += Lred[tc][0][lane];
        lB += Lred[tc][1][lane];
        #pragma unroll
        for (int ch = 0; ch < 2; ++ch) {
            float linv = 1.0f / (ch ? lB : lA);
            int t = t0 + tc * 64 + ch * 32 + ln31;
            #pragma unroll
            for (int ct = 0; ct < 2; ++ct) {
                const f32x16& ao = ch ? (ct ? oB1 : oB0) : (ct ? oA1 : oA0);
                #pragma unroll
                for (int g = 0; g < 4; ++g) {
                    int c = h * kCh + ct * 32 + 8 * g + 4 * hi;
                    float v0 = ao[4 * g + 0] * linv;
                    float v1 = ao[4 * g + 1] * linv;
                    float v2 = ao[4 * g + 2] * linv;
                    float v3 = ao[4 * g + 3] * linv;
                    *(uint2*)&attnT[((size_t)b * kT + t) * kC + c] =
                        make_uint2(pk2bf(v0, v1), pk2bf(v2, v3));
                }
            }
        }
    }
}

// ---------------------------------------------------------------------------
// Kernel 5: proj GEMM + bias + residual -> fp32 (R23 structure). R25:
// bijective XCD remap — 4 m-tiles sharing one B-tile colocate per XCD.
// ---------------------------------------------------------------------------
__global__ __launch_bounds__(256) void proj_gemm_kernel(const unsigned short* __restrict__ wpbf,
                                                        const float* __restrict__ proj_b,
                                                        const unsigned short* __restrict__ attnT,
                                                        const float* __restrict__ x,
                                                        float* __restrict__ out) {
    __shared__ __align__(16) unsigned short U[(64 + 256) * 64];
    unsigned short* As = U;
    unsigned short* Bs = U + 64 * 64;

    // XCD remap: f in [0,256); xcd gets 32 work items = 8 (t,b) x 4 m.
    int f = blockIdx.x + 16 * (blockIdx.y + 4 * blockIdx.z);
    int xcd = f & 7, idx = f >> 3;
    int g = idx >> 2, m = idx & 3;
    int tb = xcd * 8 + g;
    int t0 = (tb & 15) * 256;
    int b  = tb >> 4;
    int m0 = m * 64;
    const unsigned short* Ab = wpbf + (size_t)m0 * kC;
    const unsigned short* Bb = attnT + (size_t)b * kT * kC;

    int tid = threadIdx.x;
    int wave = tid >> 6, lane = tid & 63;
    int ln15 = lane & 15, quad = lane >> 4;
    int wm = wave >> 1, wt = wave & 1;
    int lrow = lane >> 3, lseg = lane & 7;

    f32x4 acc[2][8] = {};

    for (int k0 = 0; k0 < kC; k0 += 64) {
        __syncthreads();
        #pragma unroll
        for (int i = 0; i < 2; ++i) {
            int row = wave * 16 + i * 8 + lrow;
            int sseg = lseg ^ (row & 7);
            llds16(&Ab[(size_t)row * kC + k0 + sseg * 8], As + (wave * 2 + i) * 512);
        }
        #pragma unroll
        for (int i = 0; i < 8; ++i) {
            int row = wave * 64 + i * 8 + lrow;
            int sseg = lseg ^ (row & 7);
            llds16(&Bb[(size_t)(t0 + row) * kC + k0 + sseg * 8], Bs + (wave * 8 + i) * 512);
        }
        __syncthreads();
        #pragma unroll
        for (int ks = 0; ks < 2; ++ks) {
            bf16x8 af[2], bf[8];
            #pragma unroll
            for (int i = 0; i < 2; ++i) {
                int r = wm * 32 + i * 16 + ln15;
                af[i] = *(bf16x8*)&As[r * 64 + (((ks * 4 + quad) ^ (r & 7)) * 8)];
            }
            #pragma unroll
            for (int j = 0; j < 8; ++j) {
                int t = wt * 128 + j * 16 + ln15;
                bf[j] = *(bf16x8*)&Bs[t * 64 + (((ks * 4 + quad) ^ (t & 7)) * 8)];
            }
            #pragma unroll
            for (int i = 0; i < 2; ++i)
                #pragma unroll
                for (int j = 0; j < 8; ++j)
                    acc[i][j] = __builtin_amdgcn_mfma_f32_16x16x32_bf16(
                        af[i], bf[j], acc[i][j], 0, 0, 0);
        }
    }

    #pragma unroll
    for (int i = 0; i < 2; ++i) {
        float4 bv = *(const float4*)&proj_b[m0 + wm * 32 + i * 16 + quad * 4];
        const float* bp = (const float*)&bv;
        #pragma unroll
        for (int j = 0; j < 8; ++j) {
            int t = t0 + wt * 128 + j * 16 + ln15;
            int mbase = m0 + wm * 32 + i * 16 + quad * 4;
            #pragma unroll
            for (int r = 0; r < 4; ++r) {
                size_t off = ((size_t)b * kC + mbase + r) * kT + t;
                out[off] = acc[i][j][r] + bp[r] + x[off];
            }
        }
    }
}

// ---------------------------------------------------------------------------
extern "C" void kernel_launch(void* const* d_in, const int* in_sizes, int n_in,
                              void* d_out, int out_size, void* d_ws, size_t ws_size,
                              hipStream_t stream) {
    const float* x      = (const float*)d_in[0];
    const float* norm_w = (const float*)d_in[1];
    const float* norm_b = (const float*)d_in[2];
    const float* qkv_w  = (const float*)d_in[3];
    const float* qkv_b  = (const float*)d_in[4];
    const float* proj_w = (const float*)d_in[5];
    const float* proj_b = (const float*)d_in[6];
    float* out = (float*)d_out;

    // Workspace: stats fp32[512] (4 partials x 64 groups x {S,Q}) |
    // bf16: normT[4.19M] wbf[262144] qT kT vC attnT[4.19M each]
    float* stats = (float*)d_ws;
    unsigned short* wsbf  = (unsigned short*)((float*)d_ws + 512);
    unsigned short* normT = wsbf;
    unsigned short* wbf   = normT + (size_t)kB * kT * kC;
    unsigned short* qTp   = wbf + 262144;
    unsigned short* kTp   = qTp + (size_t)kB * kH * kT * kCh;
    unsigned short* vCp   = kTp + (size_t)kB * kH * kT * kCh;
    unsigned short* attnT = vCp + (size_t)kB * kH * kT * kCh;
    unsigned short* wpbf  = wbf + 196608;

    prep_kernel<<<384, 256, 0, stream>>>(x, stats, qkv_w, proj_w, wbf);
    gn_apply_t_kernel<<<dim3(kT / 64, kC / 64, kB), 256, 0, stream>>>(
        x, stats, norm_w, norm_b, normT);
    qkv_gemm_kernel<<<dim3(kT / 256, 12, kB), 256, 0, stream>>>(
        wbf, qkv_b, normT, qTp, kTp, vCp);
    attn_mfma_kernel<<<dim3(kT / 128, kB * kH), 256, 0, stream>>>(qTp, kTp, vCp, attnT);
    proj_gemm_kernel<<<dim3(kT / 256, kC / 64, kB), 256, 0, stream>>>(
        wpbf, proj_b, attnT, x, out);
}